// Round 14
// baseline (268.427 us; speedup 1.0000x reference)
//
#include <hip/hip_runtime.h>
#include <hip/hip_bf16.h>

#define NSP 2304   // 48*48 spatial
#define NB  4      // batch

typedef unsigned short u16;
typedef __attribute__((ext_vector_type(8))) short short8;
typedef __attribute__((ext_vector_type(4))) float f32x4;
typedef __attribute__((ext_vector_type(4))) unsigned short u16x4;

// scale * log2(e), folded into Q at QKV-GEMM epilogue: softmax p = exp2(S)
#define K1S 0.25508040852656425f

static __device__ inline u16 f2bf(float f) {
  return __builtin_bit_cast(unsigned short, __float2bfloat16(f));
}
// packed f32x2 -> bf16x2 (RNE), single VALU inst; lo16 = cvt(a), hi16 = cvt(b)
static __device__ inline unsigned cvtpk(float a, float b) {
  unsigned r;
  asm("v_cvt_pk_bf16_f32 %0, %1, %2" : "=v"(r) : "v"(a), "v"(b));
  return r;
}

// ---------------------------------------------------------------------------
// prep (grid-fused): blocks x<72 transpose x fp32 [b][256][2304] ->
// xT bf16 [b][2304][256]; block x==72 converts w_qkv+w_out fp32->bf16.
// ---------------------------------------------------------------------------
__global__ __launch_bounds__(256) void prep_fused(
    const float* __restrict__ x, const float* __restrict__ wq,
    const float* __restrict__ wo, u16* __restrict__ xT,
    u16* __restrict__ wbf) {
  const int t = threadIdx.x;
  if (blockIdx.x == 72) {  // weight conversion: 32 slices x 256 thr x 32 elems
    const int cid = blockIdx.y * 4 + blockIdx.z;  // 0..31
    const int base = cid * 8192;
#pragma unroll
    for (int i = 0; i < 8; ++i) {
      int idx = base + (i * 256 + t) * 4;
      float4 v;
      if (idx < 196608) v = *(const float4*)(wq + idx);
      else              v = *(const float4*)(wo + (idx - 196608));
      u16x4 p = {f2bf(v.x), f2bf(v.y), f2bf(v.z), f2bf(v.w)};
      *(u16x4*)(wbf + idx) = p;
    }
    return;
  }
  __shared__ float tile[32][33];
  const int n0 = blockIdx.x * 32, c0 = blockIdx.y * 32, b = blockIdx.z;
  const float* xb = x + ((size_t)b * 256 + c0) * NSP + n0;
#pragma unroll
  for (int e = t; e < 1024; e += 256) {
    int cc = e >> 5, nn = e & 31;
    tile[cc][nn] = xb[(size_t)cc * NSP + nn];
  }
  __syncthreads();
  u16* xTb = xT + ((size_t)b * NSP + n0) * 256 + c0;
#pragma unroll
  for (int e = t; e < 1024; e += 256) {
    int nn = e >> 5, cc = e & 31;
    xTb[(size_t)nn * 256 + cc] = f2bf(tile[cc][nn]);
  }
}

// ---------------------------------------------------------------------------
// bf16 MFMA GEMM (LDS-staged): D = A (Mx256) * B[b](Nx256)^T
// 64x64 tile, 4 waves (2x2 of 32x32), whole K=256 staged once.
// EPI 0: rows <256 q (pre-scaled K1S), 256..511 k -> qkT[b][n][512] bf16;
//        rows >=512 v -> vbuf[b][256][2304] bf16.
// EPI 1: fp32 out + bias.
// ---------------------------------------------------------------------------
template <int EPI>
__global__ __launch_bounds__(256) void gemm_mfma(
    const u16* __restrict__ A, const u16* __restrict__ B,
    u16* __restrict__ qkT, u16* __restrict__ vbuf,
    float* __restrict__ outf, const float* __restrict__ bias, int N) {
  __shared__ u16 As[64][264];
  __shared__ u16 Bs[64][264];
  const int t = threadIdx.x, lane = t & 63, wid = t >> 6;
  const int lo = lane & 15, g = lane >> 4;
  const int wr = wid >> 1, wc = wid & 1;
  const int row0 = blockIdx.y * 64, col0 = blockIdx.x * 64, b = blockIdx.z;

  const int sr = t >> 2, c4 = t & 3;
  const u16* Arow = A + (size_t)(row0 + sr) * 256;
  const u16* Brow = B + ((size_t)b * N + col0 + sr) * 256;
#pragma unroll
  for (int i = 0; i < 8; ++i) {
    int col = (c4 + 4 * i) * 8;
    *(uint4*)&As[sr][col] = *(const uint4*)&Arow[col];
    *(uint4*)&Bs[sr][col] = *(const uint4*)&Brow[col];
  }
  __syncthreads();

  f32x4 acc[2][2];
#pragma unroll
  for (int i = 0; i < 2; ++i)
#pragma unroll
    for (int j = 0; j < 2; ++j) acc[i][j] = (f32x4){0, 0, 0, 0};

  const int ar0 = wr * 32 + lo, br0 = wc * 32 + lo;
#pragma unroll
  for (int kk = 0; kk < 8; ++kk) {
    int kc = kk * 32 + g * 8;
    short8 a0 = *(const short8*)&As[ar0][kc];
    short8 a1 = *(const short8*)&As[ar0 + 16][kc];
    short8 b0 = *(const short8*)&Bs[br0][kc];
    short8 b1 = *(const short8*)&Bs[br0 + 16][kc];
    acc[0][0] = __builtin_amdgcn_mfma_f32_16x16x32_bf16(a0, b0, acc[0][0], 0, 0, 0);
    acc[0][1] = __builtin_amdgcn_mfma_f32_16x16x32_bf16(a0, b1, acc[0][1], 0, 0, 0);
    acc[1][0] = __builtin_amdgcn_mfma_f32_16x16x32_bf16(a1, b0, acc[1][0], 0, 0, 0);
    acc[1][1] = __builtin_amdgcn_mfma_f32_16x16x32_bf16(a1, b1, acc[1][1], 0, 0, 0);
  }

  const float qs = (EPI == 0 && row0 < 256) ? K1S : 1.0f;
#pragma unroll
  for (int m2 = 0; m2 < 2; ++m2)
#pragma unroll
    for (int n2 = 0; n2 < 2; ++n2) {
      int m = row0 + wr * 32 + m2 * 16 + g * 4;
      int n = col0 + wc * 32 + n2 * 16 + lo;
      if constexpr (EPI == 0) {
        if (row0 < 512) {  // q,k -> transposed qkT[b][n][m..m+3]
          u16x4 pk = {f2bf(acc[m2][n2][0] * qs), f2bf(acc[m2][n2][1] * qs),
                      f2bf(acc[m2][n2][2] * qs), f2bf(acc[m2][n2][3] * qs)};
          *(u16x4*)(qkT + ((size_t)b * NSP + n) * 512 + m) = pk;
        } else {           // v -> natural vbuf[b][m-512][n]
#pragma unroll
          for (int r = 0; r < 4; ++r)
            vbuf[((size_t)b * 256 + (m - 512 + r)) * NSP + n] =
                f2bf(acc[m2][n2][r]);
        }
      } else {
#pragma unroll
        for (int r = 0; r < 4; ++r)
          outf[((size_t)b * 256 + m + r) * NSP + n] =
              acc[m2][n2][r] + bias[m + r];
      }
    }
}

// ---------------------------------------------------------------------------
// MFMA flash attention, ZERO LDS / ZERO BARRIERS.
// K/V fragments come straight from L2 (XCD swizzle keeps each (b,h)'s 300 KB
// on one XCD -> L2-resident, proven r10 FETCH_SIZE). Explicit 2-deep register
// double-buffer (named A/B sets): COMPUTE(A,s) LOAD(A,s+2) COMPUTE(B,s+1)
// LOAD(B,s+3) -> one full strip of compute covers each load's L2 latency,
// and 4.5 independent waves/SIMD (no barriers!) fill the rest.
// 16 q/wave; P in-register (sigma trick, cvt_pk); row-sum l via ones-MFMA.
// ---------------------------------------------------------------------------
struct KVregs {
  uint4 k[4];   // K rows j0 + 16i + lo, 16B of d
  uint2 v[8];   // V rows {lo, 16+lo} x j-positions {4g,16+4g,32+4g,48+4g}
};

__global__ __launch_bounds__(256) void attn_mfma(
    const u16* __restrict__ qkT, const u16* __restrict__ vbuf,
    u16* __restrict__ attnoT) {
  const int jb = blockIdx.x;
  const int h = jb & 7;
  const int qq = jb >> 3;
  const int it = qq % 36;
  const int b  = qq / 36;
  const int t = threadIdx.x, lane = t & 63, w = t >> 6;
  const int lo = lane & 15, g = lane >> 4;
  const int i0 = it * 64;

  const u16* qkTb = qkT + (size_t)b * NSP * 512;
  const u16* vb   = vbuf + ((size_t)b * 256 + h * 32) * NSP;
  u16* ob = attnoT + ((size_t)b * NSP + i0) * 256 + h * 32;

  // Q fragment: query i0 + w*16 + lo (pre-scaled by K1S upstream)
  short8 qf = *(const short8*)(qkTb + (size_t)(i0 + w * 16 + lo) * 512 +
                               h * 32 + g * 8);

  // per-lane global bases
  const u16* kbase = qkTb + 256 + h * 32 + g * 8;        // + j*512
  const u16* v0base = vb + (size_t)lo * NSP + 4 * g;     // + j0 + {0,16,32,48}
  const u16* v1base = vb + (size_t)(16 + lo) * NSP + 4 * g;

  short8 ones;
#pragma unroll
  for (int e = 0; e < 8; ++e) ones[e] = (short)0x3F80;  // bf16 1.0

  f32x4 a0 = {0, 0, 0, 0}, a1 = {0, 0, 0, 0}, al = {0, 0, 0, 0};

  KVregs A, B;
#define LOADSET(S, s_)                                                        \
  {                                                                           \
    const int j0_ = (s_)*64;                                                  \
    _Pragma("unroll") for (int i = 0; i < 4; ++i)                             \
        S.k[i] = *(const uint4*)(kbase + (size_t)(j0_ + 16 * i + lo) * 512);  \
    _Pragma("unroll") for (int i = 0; i < 4; ++i) {                           \
      S.v[i]     = *(const uint2*)(v0base + j0_ + 16 * i);                    \
      S.v[4 + i] = *(const uint2*)(v1base + j0_ + 16 * i);                    \
    }                                                                         \
  }

#define COMPUTE(S)                                                            \
  {                                                                           \
    short8 kf0 = __builtin_bit_cast(short8, S.k[0]);                          \
    short8 kf1 = __builtin_bit_cast(short8, S.k[1]);                          \
    short8 kf2 = __builtin_bit_cast(short8, S.k[2]);                          \
    short8 kf3 = __builtin_bit_cast(short8, S.k[3]);                          \
    __builtin_amdgcn_s_setprio(1);                                            \
    f32x4 sv0 = __builtin_amdgcn_mfma_f32_16x16x32_bf16(                      \
        kf0, qf, (f32x4){0, 0, 0, 0}, 0, 0, 0);                               \
    f32x4 sv1 = __builtin_amdgcn_mfma_f32_16x16x32_bf16(                      \
        kf1, qf, (f32x4){0, 0, 0, 0}, 0, 0, 0);                               \
    f32x4 sv2 = __builtin_amdgcn_mfma_f32_16x16x32_bf16(                      \
        kf2, qf, (f32x4){0, 0, 0, 0}, 0, 0, 0);                               \
    f32x4 sv3 = __builtin_amdgcn_mfma_f32_16x16x32_bf16(                      \
        kf3, qf, (f32x4){0, 0, 0, 0}, 0, 0, 0);                               \
    __builtin_amdgcn_s_setprio(0);                                            \
    f32x4 e0, e1, e2, e3;                                                     \
    _Pragma("unroll") for (int r = 0; r < 4; ++r) {                           \
      e0[r] = __builtin_amdgcn_exp2f(sv0[r]);                                 \
      e1[r] = __builtin_amdgcn_exp2f(sv1[r]);                                 \
      e2[r] = __builtin_amdgcn_exp2f(sv2[r]);                                 \
      e3[r] = __builtin_amdgcn_exp2f(sv3[r]);                                 \
    }                                                                         \
    uint4 P0 = {cvtpk(e0[0], e0[1]), cvtpk(e0[2], e0[3]),                     \
                cvtpk(e1[0], e1[1]), cvtpk(e1[2], e1[3])};                    \
    uint4 P1 = {cvtpk(e2[0], e2[1]), cvtpk(e2[2], e2[3]),                     \
                cvtpk(e3[0], e3[1]), cvtpk(e3[2], e3[3])};                    \
    short8 pf0 = __builtin_bit_cast(short8, P0);                              \
    short8 pf1 = __builtin_bit_cast(short8, P1);                              \
    uint4 V00 = {S.v[0].x, S.v[0].y, S.v[1].x, S.v[1].y};                     \
    uint4 V01 = {S.v[2].x, S.v[2].y, S.v[3].x, S.v[3].y};                     \
    uint4 V10 = {S.v[4].x, S.v[4].y, S.v[5].x, S.v[5].y};                     \
    uint4 V11 = {S.v[6].x, S.v[6].y, S.v[7].x, S.v[7].y};                     \
    short8 vf00 = __builtin_bit_cast(short8, V00);                            \
    short8 vf01 = __builtin_bit_cast(short8, V01);                            \
    short8 vf10 = __builtin_bit_cast(short8, V10);                            \
    short8 vf11 = __builtin_bit_cast(short8, V11);                            \
    __builtin_amdgcn_s_setprio(1);                                            \
    a0 = __builtin_amdgcn_mfma_f32_16x16x32_bf16(pf0, vf00, a0, 0, 0, 0);     \
    a1 = __builtin_amdgcn_mfma_f32_16x16x32_bf16(pf0, vf10, a1, 0, 0, 0);     \
    al = __builtin_amdgcn_mfma_f32_16x16x32_bf16(pf0, ones, al, 0, 0, 0);     \
    a0 = __builtin_amdgcn_mfma_f32_16x16x32_bf16(pf1, vf01, a0, 0, 0, 0);     \
    a1 = __builtin_amdgcn_mfma_f32_16x16x32_bf16(pf1, vf11, a1, 0, 0, 0);     \
    al = __builtin_amdgcn_mfma_f32_16x16x32_bf16(pf1, ones, al, 0, 0, 0);     \
    __builtin_amdgcn_s_setprio(0);                                            \
  }

  LOADSET(A, 0);
  LOADSET(B, 1);
#pragma unroll 2
  for (int s = 0; s < 36; s += 2) {
    COMPUTE(A);
    if (s + 2 < 36) LOADSET(A, s + 2);
    COMPUTE(B);
    if (s + 3 < 36) LOADSET(B, s + 3);
  }

  // ---- normalize + bf16 store to attnoT[n][c] ----
#pragma unroll
  for (int r = 0; r < 4; ++r) {
    float inv = 1.0f / al[r];
    int row = w * 16 + g * 4 + r;
    ob[(size_t)row * 256 + lo]      = f2bf(a0[r] * inv);
    ob[(size_t)row * 256 + 16 + lo] = f2bf(a1[r] * inv);
  }
#undef LOADSET
#undef COMPUTE
}

// ---------------------------------------------------------------------------
extern "C" void kernel_launch(void* const* d_in, const int* in_sizes, int n_in,
                              void* d_out, int out_size, void* d_ws, size_t ws_size,
                              hipStream_t stream) {
  const float* x     = (const float*)d_in[0];  // [4][256][48][48]
  const float* w_qkv = (const float*)d_in[1];  // [768][256]
  const float* w_out = (const float*)d_in[2];  // [256][256]
  const float* b_out = (const float*)d_in[3];  // [256]
  float* out = (float*)d_out;                  // [4][256][2304]

  u16* wbf    = (u16*)d_ws;                    // wqkv 196608 then wout 65536
  u16* xT     = wbf + 262144;                  // [4][2304][256]
  u16* qkT    = xT + (size_t)NB * NSP * 256;   // [4][2304][512]
  u16* vbuf   = qkT + (size_t)NB * NSP * 512;  // [4][256][2304]
  u16* attnoT = vbuf + (size_t)NB * 256 * NSP; // [4][2304][256]

  dim3 blk(256);
  prep_fused<<<dim3(73, 8, NB), blk, 0, stream>>>(x, w_qkv, w_out, xT, wbf);
  gemm_mfma<0><<<dim3(NSP / 64, 12, NB), blk, 0, stream>>>(
      wbf, xT, qkT, vbuf, nullptr, nullptr, NSP);
  attn_mfma<<<dim3(1152), blk, 0, stream>>>(qkT, vbuf, attnoT);
  gemm_mfma<1><<<dim3(NSP / 64, 4, NB), blk, 0, stream>>>(
      wbf + 196608, attnoT, nullptr, nullptr, out, b_out, NSP);
}

// Round 15
// 83.360 us; speedup vs baseline: 3.2201x; 3.2201x over previous
//
#include <hip/hip_runtime.h>
#include <hip/hip_bf16.h>

#define NSP 2304   // 48*48 spatial
#define NB  4      // batch

typedef unsigned short u16;
typedef __attribute__((ext_vector_type(8))) short short8;
typedef __attribute__((ext_vector_type(4))) float f32x4;
typedef __attribute__((ext_vector_type(4))) unsigned short u16x4;

// scale * log2(e), folded into Q at QKV-GEMM epilogue: softmax p = exp2(S)
#define K1S 0.25508040852656425f

static __device__ inline u16 f2bf(float f) {
  return __builtin_bit_cast(unsigned short, __float2bfloat16(f));
}
// packed f32x2 -> bf16x2 (RNE), single VALU inst; lo16 = cvt(a), hi16 = cvt(b)
static __device__ inline unsigned cvtpk(float a, float b) {
  unsigned r;
  asm("v_cvt_pk_bf16_f32 %0, %1, %2" : "=v"(r) : "v"(a), "v"(b));
  return r;
}

// ---------------------------------------------------------------------------
// bf16 MFMA GEMM with FUSED fp32->bf16 conversion (no prep kernels).
// D = W (Mx256 fp32) * B[b] (Nx256)^T, 64x64 tile, 4 waves (2x2 of 32x32).
// A staged from fp32 weights with cvtpk. B:
//   EPI 0: built by 4x4 transpose-convert from x fp32 [b][256][2304]
//          (Bs[n][c] = bf16(x[b][c][col0+n])) — kills transpose_x.
//   EPI 1: attnoT bf16 rows, staged as before.
// EPI 0 epilogue: rows <256 q (pre-scaled K1S), 256..511 k -> qkT[b][n][512];
//                 rows >=512 v -> vbuf[b][256][2304].
// EPI 1 epilogue: fp32 out + bias.
// ---------------------------------------------------------------------------
template <int EPI>
__global__ __launch_bounds__(256) void gemm_mfma(
    const float* __restrict__ W, const float* __restrict__ x,
    const u16* __restrict__ Bbf,
    u16* __restrict__ qkT, u16* __restrict__ vbuf,
    float* __restrict__ outf, const float* __restrict__ bias, int N) {
  __shared__ u16 As[64][264];
  __shared__ u16 Bs[64][264];
  const int t = threadIdx.x, lane = t & 63, wid = t >> 6;
  const int lo = lane & 15, g = lane >> 4;
  const int wr = wid >> 1, wc = wid & 1;
  const int row0 = blockIdx.y * 64, col0 = blockIdx.x * 64, b = blockIdx.z;

  // ---- A: fp32 weights -> bf16 LDS (cvtpk pairs) ----
  {
    const int sr = t >> 2, c4 = (t & 3) * 64;
    const float* Arow = W + (size_t)(row0 + sr) * 256 + c4;
#pragma unroll
    for (int i = 0; i < 8; ++i) {
      float4 va = *(const float4*)(Arow + i * 8);
      float4 vb = *(const float4*)(Arow + i * 8 + 4);
      uint4 p = {cvtpk(va.x, va.y), cvtpk(va.z, va.w),
                 cvtpk(vb.x, vb.y), cvtpk(vb.z, vb.w)};
      *(uint4*)&As[sr][c4 + i * 8] = p;
    }
  }
  // ---- B ----
  if constexpr (EPI == 0) {
    // transpose-convert from x: Bs[n][c] = bf16(x[b][c][col0+n])
    const float* xb = x + (size_t)b * 256 * NSP + col0;
    const int n0 = (t & 15) * 4;
#pragma unroll
    for (int ci = 0; ci < 4; ++ci) {
      int c = ci * 64 + (t >> 4) * 4;
      float4 r0 = *(const float4*)(xb + (size_t)(c + 0) * NSP + n0);
      float4 r1 = *(const float4*)(xb + (size_t)(c + 1) * NSP + n0);
      float4 r2 = *(const float4*)(xb + (size_t)(c + 2) * NSP + n0);
      float4 r3 = *(const float4*)(xb + (size_t)(c + 3) * NSP + n0);
      *(u16x4*)&Bs[n0 + 0][c] =
          (u16x4){f2bf(r0.x), f2bf(r1.x), f2bf(r2.x), f2bf(r3.x)};
      *(u16x4*)&Bs[n0 + 1][c] =
          (u16x4){f2bf(r0.y), f2bf(r1.y), f2bf(r2.y), f2bf(r3.y)};
      *(u16x4*)&Bs[n0 + 2][c] =
          (u16x4){f2bf(r0.z), f2bf(r1.z), f2bf(r2.z), f2bf(r3.z)};
      *(u16x4*)&Bs[n0 + 3][c] =
          (u16x4){f2bf(r0.w), f2bf(r1.w), f2bf(r2.w), f2bf(r3.w)};
    }
  } else {
    const int sr = t >> 2, c4 = (t & 3) * 64;
    const u16* Brow = Bbf + ((size_t)b * N + col0 + sr) * 256 + c4;
#pragma unroll
    for (int i = 0; i < 8; ++i)
      *(uint4*)&Bs[sr][c4 + i * 8] = *(const uint4*)(Brow + i * 8);
  }
  __syncthreads();

  f32x4 acc[2][2];
#pragma unroll
  for (int i = 0; i < 2; ++i)
#pragma unroll
    for (int j = 0; j < 2; ++j) acc[i][j] = (f32x4){0, 0, 0, 0};

  const int ar0 = wr * 32 + lo, br0 = wc * 32 + lo;
#pragma unroll
  for (int kk = 0; kk < 8; ++kk) {
    int kc = kk * 32 + g * 8;
    short8 a0 = *(const short8*)&As[ar0][kc];
    short8 a1 = *(const short8*)&As[ar0 + 16][kc];
    short8 b0 = *(const short8*)&Bs[br0][kc];
    short8 b1 = *(const short8*)&Bs[br0 + 16][kc];
    acc[0][0] = __builtin_amdgcn_mfma_f32_16x16x32_bf16(a0, b0, acc[0][0], 0, 0, 0);
    acc[0][1] = __builtin_amdgcn_mfma_f32_16x16x32_bf16(a0, b1, acc[0][1], 0, 0, 0);
    acc[1][0] = __builtin_amdgcn_mfma_f32_16x16x32_bf16(a1, b0, acc[1][0], 0, 0, 0);
    acc[1][1] = __builtin_amdgcn_mfma_f32_16x16x32_bf16(a1, b1, acc[1][1], 0, 0, 0);
  }

  const float qs = (EPI == 0 && row0 < 256) ? K1S : 1.0f;
#pragma unroll
  for (int m2 = 0; m2 < 2; ++m2)
#pragma unroll
    for (int n2 = 0; n2 < 2; ++n2) {
      int m = row0 + wr * 32 + m2 * 16 + g * 4;
      int n = col0 + wc * 32 + n2 * 16 + lo;
      if constexpr (EPI == 0) {
        if (row0 < 512) {  // q,k -> transposed qkT[b][n][m..m+3]
          u16x4 pk = {f2bf(acc[m2][n2][0] * qs), f2bf(acc[m2][n2][1] * qs),
                      f2bf(acc[m2][n2][2] * qs), f2bf(acc[m2][n2][3] * qs)};
          *(u16x4*)(qkT + ((size_t)b * NSP + n) * 512 + m) = pk;
        } else {           // v -> natural vbuf[b][m-512][n]
#pragma unroll
          for (int r = 0; r < 4; ++r)
            vbuf[((size_t)b * 256 + (m - 512 + r)) * NSP + n] =
                f2bf(acc[m2][n2][r]);
        }
      } else {
#pragma unroll
        for (int r = 0; r < 4; ++r)
          outf[((size_t)b * 256 + m + r) * NSP + n] =
              acc[m2][n2][r] + bias[m + r];
      }
    }
}

// ---------------------------------------------------------------------------
// MFMA flash attention (r11, best measured: 51.8 us).
// 2-wave 128-thr blocks, 48 queries/wave (3 Q-frags) -> K/V fragment reads
// amortized 3x. KVBLK=128 (18 strips, 1 barrier each, double-buffered).
// Grid 768, XCD-swizzled (h = blockIdx%8) -> each (b,h)'s K/V L2-resident.
// P in-register (sigma trick); V stored PERMUTED so each V-fragment is one
// b128; Kt stride 42, Vs stride 138. Row-sum l via ones-MFMA. setprio(1)
// around MFMA clusters.
// ---------------------------------------------------------------------------
__global__ __launch_bounds__(128, 2) void attn_mfma(
    const u16* __restrict__ qkT, const u16* __restrict__ vbuf,
    u16* __restrict__ attnoT) {
  const int jb = blockIdx.x;
  const int h = jb & 7;
  const int qq = jb >> 3;
  const int it = qq % 24;
  const int b  = qq / 24;
  const int t = threadIdx.x, lane = t & 63, w = t >> 6;
  const int lo = lane & 15, g = lane >> 4;
  const int i0 = it * 96;

  const u16* qkTb = qkT + (size_t)b * NSP * 512;
  const u16* vb   = vbuf + ((size_t)b * 256 + h * 32) * NSP;
  u16* ob = attnoT + ((size_t)b * NSP + i0) * 256 + h * 32;

  __shared__ u16 Kt[2][128][42];   // [key j][d]
  __shared__ u16 Vs[2][32][138];   // [d][permuted j]

  // three Q fragments: queries i0 + w*48 + qh*16 + lo (pre-scaled by K1S)
  short8 qf[3];
#pragma unroll
  for (int qh = 0; qh < 3; ++qh)
    qf[qh] = *(const short8*)(qkTb +
              (size_t)(i0 + w * 48 + qh * 16 + lo) * 512 + h * 32 + g * 8);

  const int kr = t >> 2, kp = (t & 3) * 8;
  const int vr = t >> 4, vjp = (t & 15) * 8;
  const int pc0 = (vjp & ~31) | (8 * ((vjp >> 2) & 3) + 4 * ((vjp >> 4) & 1));
  const u16* ksrc = qkTb + 256 + h * 32 + kp;            // + (j0+row)*512
  const u16* vsrc = vb + (size_t)vr * NSP + vjp;         // + 8i*NSP + j0

  uint4 kv[4], vv[4];
#pragma unroll
  for (int i = 0; i < 4; ++i) {
    kv[i] = *(const uint4*)(ksrc + (size_t)(kr + 32 * i) * 512);
    vv[i] = *(const uint4*)(vsrc + (size_t)(8 * i) * NSP);
  }
#pragma unroll
  for (int i = 0; i < 4; ++i) {
    *(uint4*)&Kt[0][kr + 32 * i][kp] = kv[i];
    *(uint2*)&Vs[0][vr + 8 * i][pc0]     = make_uint2(vv[i].x, vv[i].y);
    *(uint2*)&Vs[0][vr + 8 * i][pc0 + 8] = make_uint2(vv[i].z, vv[i].w);
  }
  __syncthreads();

  short8 ones;
#pragma unroll
  for (int e = 0; e < 8; ++e) ones[e] = (short)0x3F80;  // bf16 1.0

  f32x4 a0[3], a1[3], al[3];
#pragma unroll
  for (int qh = 0; qh < 3; ++qh) {
    a0[qh] = (f32x4){0, 0, 0, 0};
    a1[qh] = (f32x4){0, 0, 0, 0};
    al[qh] = (f32x4){0, 0, 0, 0};
  }

  for (int s = 0; s < 18; ++s) {
    const int cur = s & 1;
    if (s + 1 < 18) {  // prefetch next strip into regs (hidden under compute)
      const int j0n = (s + 1) * 128;
#pragma unroll
      for (int i = 0; i < 4; ++i) {
        kv[i] = *(const uint4*)(ksrc + (size_t)(j0n + kr + 32 * i) * 512);
        vv[i] = *(const uint4*)(vsrc + j0n + (size_t)(8 * i) * NSP);
      }
    }

#pragma unroll
    for (int h2 = 0; h2 < 2; ++h2) {
      short8 kf0 = *(const short8*)&Kt[cur][h2 * 64 + lo][g * 8];
      short8 kf1 = *(const short8*)&Kt[cur][h2 * 64 + 16 + lo][g * 8];
      short8 kf2 = *(const short8*)&Kt[cur][h2 * 64 + 32 + lo][g * 8];
      short8 kf3 = *(const short8*)&Kt[cur][h2 * 64 + 48 + lo][g * 8];
      short8 vf00 = *(const short8*)&Vs[cur][lo][h2 * 64 + 8 * g];
      short8 vf01 = *(const short8*)&Vs[cur][lo][h2 * 64 + 32 + 8 * g];
      short8 vf10 = *(const short8*)&Vs[cur][16 + lo][h2 * 64 + 8 * g];
      short8 vf11 = *(const short8*)&Vs[cur][16 + lo][h2 * 64 + 32 + 8 * g];

#pragma unroll
      for (int qh = 0; qh < 3; ++qh) {
        __builtin_amdgcn_s_setprio(1);
        f32x4 sv0 = __builtin_amdgcn_mfma_f32_16x16x32_bf16(kf0, qf[qh], (f32x4){0,0,0,0}, 0, 0, 0);
        f32x4 sv1 = __builtin_amdgcn_mfma_f32_16x16x32_bf16(kf1, qf[qh], (f32x4){0,0,0,0}, 0, 0, 0);
        f32x4 sv2 = __builtin_amdgcn_mfma_f32_16x16x32_bf16(kf2, qf[qh], (f32x4){0,0,0,0}, 0, 0, 0);
        f32x4 sv3 = __builtin_amdgcn_mfma_f32_16x16x32_bf16(kf3, qf[qh], (f32x4){0,0,0,0}, 0, 0, 0);
        __builtin_amdgcn_s_setprio(0);

        f32x4 e0, e1, e2, e3;
#pragma unroll
        for (int r = 0; r < 4; ++r) {
          e0[r] = __builtin_amdgcn_exp2f(sv0[r]);
          e1[r] = __builtin_amdgcn_exp2f(sv1[r]);
          e2[r] = __builtin_amdgcn_exp2f(sv2[r]);
          e3[r] = __builtin_amdgcn_exp2f(sv3[r]);
        }
        uint4 P0 = {cvtpk(e0[0], e0[1]), cvtpk(e0[2], e0[3]),
                    cvtpk(e1[0], e1[1]), cvtpk(e1[2], e1[3])};
        uint4 P1 = {cvtpk(e2[0], e2[1]), cvtpk(e2[2], e2[3]),
                    cvtpk(e3[0], e3[1]), cvtpk(e3[2], e3[3])};
        short8 pf0 = __builtin_bit_cast(short8, P0);
        short8 pf1 = __builtin_bit_cast(short8, P1);

        __builtin_amdgcn_s_setprio(1);
        a0[qh] = __builtin_amdgcn_mfma_f32_16x16x32_bf16(pf0, vf00, a0[qh], 0, 0, 0);
        a1[qh] = __builtin_amdgcn_mfma_f32_16x16x32_bf16(pf0, vf10, a1[qh], 0, 0, 0);
        al[qh] = __builtin_amdgcn_mfma_f32_16x16x32_bf16(pf0, ones, al[qh], 0, 0, 0);
        a0[qh] = __builtin_amdgcn_mfma_f32_16x16x32_bf16(pf1, vf01, a0[qh], 0, 0, 0);
        a1[qh] = __builtin_amdgcn_mfma_f32_16x16x32_bf16(pf1, vf11, a1[qh], 0, 0, 0);
        al[qh] = __builtin_amdgcn_mfma_f32_16x16x32_bf16(pf1, ones, al[qh], 0, 0, 0);
        __builtin_amdgcn_s_setprio(0);
      }
    }

    if (s + 1 < 18) {  // write next strip into the other buffer
#pragma unroll
      for (int i = 0; i < 4; ++i) {
        *(uint4*)&Kt[cur ^ 1][kr + 32 * i][kp] = kv[i];
        *(uint2*)&Vs[cur ^ 1][vr + 8 * i][pc0]     = make_uint2(vv[i].x, vv[i].y);
        *(uint2*)&Vs[cur ^ 1][vr + 8 * i][pc0 + 8] = make_uint2(vv[i].z, vv[i].w);
      }
    }
    __syncthreads();
  }

  // ---- normalize + bf16 store to attnoT[n][c] ----
#pragma unroll
  for (int qh = 0; qh < 3; ++qh)
#pragma unroll
    for (int r = 0; r < 4; ++r) {
      float inv = 1.0f / al[qh][r];
      int row = w * 48 + qh * 16 + g * 4 + r;
      ob[(size_t)row * 256 + lo]      = f2bf(a0[qh][r] * inv);
      ob[(size_t)row * 256 + 16 + lo] = f2bf(a1[qh][r] * inv);
    }
}

// ---------------------------------------------------------------------------
extern "C" void kernel_launch(void* const* d_in, const int* in_sizes, int n_in,
                              void* d_out, int out_size, void* d_ws, size_t ws_size,
                              hipStream_t stream) {
  const float* x     = (const float*)d_in[0];  // [4][256][48][48]
  const float* w_qkv = (const float*)d_in[1];  // [768][256]
  const float* w_out = (const float*)d_in[2];  // [256][256]
  const float* b_out = (const float*)d_in[3];  // [256]
  float* out = (float*)d_out;                  // [4][256][2304]

  u16* qkT    = (u16*)d_ws;                    // [4][2304][512]
  u16* vbuf   = qkT + (size_t)NB * NSP * 512;  // [4][256][2304]
  u16* attnoT = vbuf + (size_t)NB * 256 * NSP; // [4][2304][256]

  dim3 blk(256);
  // QKV projection (A = w_qkv fp32, B = transpose-converted x) -> qkT + vbuf
  gemm_mfma<0><<<dim3(NSP / 64, 12, NB), blk, 0, stream>>>(
      w_qkv, x, nullptr, qkT, vbuf, nullptr, nullptr, NSP);
  // attention (r11 kernel)
  attn_mfma<<<dim3(768), dim3(128), 0, stream>>>(qkT, vbuf, attnoT);
  // output projection + bias (A = w_out fp32, B = attnoT bf16) -> fp32 out
  gemm_mfma<1><<<dim3(NSP / 64, 4, NB), blk, 0, stream>>>(
      w_out, nullptr, attnoT, nullptr, nullptr, out, b_out, NSP);
}